// Round 5
// baseline (385.589 us; speedup 1.0000x reference)
//
#include <hip/hip_runtime.h>
#include <cstdint>
#include <cstddef>

typedef unsigned short u16;
typedef unsigned int   u32;

#define D_IN  256
#define D_H   128
#define D_OUT 64

__device__ __forceinline__ float bf2f(u16 u){
  union { u32 i; float f; } v; v.i = ((u32)u) << 16; return v.f;
}
__device__ __forceinline__ u16 f2bf(float f){
  union { float f; u32 i; } v; v.f = f;
  u32 r = (v.i + 0x7fffu + ((v.i >> 16) & 1u)) >> 16;
  return (u16)r;
}

// ---------------- graph prep ----------------
__global__ void k_zero(int* __restrict__ p, int n){
  int i = blockIdx.x * 256 + threadIdx.x;
  if (i < n) p[i] = 0;
}

__global__ void k_deg(const int* __restrict__ dst, int E, int* __restrict__ deg){
  int e = blockIdx.x * 256 + threadIdx.x;
  if (e < E) atomicAdd(&deg[dst[e]], 1);
}

__global__ __launch_bounds__(256) void k_bsum(const int* __restrict__ deg, int N,
                                              int* __restrict__ bsum){
  __shared__ int s[256];
  int tid = threadIdx.x;
  int i = blockIdx.x * 256 + tid;
  s[tid] = (i < N) ? deg[i] : 0;
  __syncthreads();
  for (int o = 128; o > 0; o >>= 1){
    if (tid < o) s[tid] += s[tid + o];
    __syncthreads();
  }
  if (tid == 0) bsum[blockIdx.x] = s[0];
}

__global__ __launch_bounds__(256) void k_bscan(int* __restrict__ bsum, int nb){
  __shared__ int s[256];
  int tid = threadIdx.x;
  int v = (tid < nb) ? bsum[tid] : 0;
  s[tid] = v;
  __syncthreads();
  for (int o = 1; o < 256; o <<= 1){
    int t = (tid >= o) ? s[tid - o] : 0;
    __syncthreads();
    s[tid] += t;
    __syncthreads();
  }
  if (tid < nb) bsum[tid] = s[tid] - v;
}

__global__ __launch_bounds__(256) void k_off(const int* __restrict__ deg, int N,
                                             const int* __restrict__ bsum,
                                             int* __restrict__ off, int* __restrict__ cursor,
                                             float* __restrict__ dinv){
  __shared__ int s[256];
  int tid = threadIdx.x;
  int i = blockIdx.x * 256 + tid;
  int v = (i < N) ? deg[i] : 0;
  s[tid] = v;
  __syncthreads();
  for (int o = 1; o < 256; o <<= 1){
    int t = (tid >= o) ? s[tid - o] : 0;
    __syncthreads();
    s[tid] += t;
    __syncthreads();
  }
  if (i < N){
    int excl = s[tid] - v + bsum[blockIdx.x];
    off[i] = excl;
    cursor[i] = excl;
    dinv[i] = rsqrtf((float)v + 1.0f);
  }
}

__global__ void k_fill(const int* __restrict__ src, const int* __restrict__ dst,
                       int E, int* __restrict__ cursor, int* __restrict__ csr){
  int e = blockIdx.x * 256 + threadIdx.x;
  if (e < E){
    int d = dst[e];
    int p = atomicAdd(&cursor[d], 1);
    csr[p] = src[e];
  }
}

// ---------------- GEMM1: [M x 256](f32 gathered from xs/xt) @ W0[256 x 128](f32) -> h1 bf16 ----
__global__ __launch_bounds__(256) void k_gemm1(
    const float* __restrict__ Xs, const float* __restrict__ Xt,
    const float* __restrict__ W, int M, int n_s,
    u16* __restrict__ out)
{
  constexpr int BM = 128, BK = 16, BN = 128, TN = 8, K = D_IN;
  __shared__ float As[BK][BM + 4];
  __shared__ float Bs[BK][BN + 4];

  const int t  = threadIdx.x;
  const int tx = t & 15;
  const int ty = t >> 4;
  const int row0 = blockIdx.x * BM;

  float acc[8][TN];
  #pragma unroll
  for (int i = 0; i < 8; i++)
    #pragma unroll
    for (int j = 0; j < TN; j++) acc[i][j] = 0.f;

  const int ar = t >> 1;           // 0..127
  const int ak = (t & 1) * 8;      // 0 or 8
  const int r  = row0 + ar;
  const float* xp = nullptr;
  if (r < M) xp = (r < n_s) ? (Xs + (size_t)r * K) : (Xt + (size_t)(r - n_s) * K);

  const int br = t >> 4;           // 0..15  (8 W elems per thread)
  const int bc = (t & 15) * 8;

  for (int k0 = 0; k0 < K; k0 += BK){
    float4 a0, a1;
    if (xp){
      const float4* p4 = (const float4*)(xp + k0 + ak);
      a0 = p4[0]; a1 = p4[1];
    } else {
      a0 = make_float4(0,0,0,0); a1 = a0;
    }
    const float4* w4 = (const float4*)(W + (size_t)(br + k0) * BN + bc);
    float4 b0 = w4[0], b1 = w4[1];

    __syncthreads();
    As[ak+0][ar]=a0.x; As[ak+1][ar]=a0.y; As[ak+2][ar]=a0.z; As[ak+3][ar]=a0.w;
    As[ak+4][ar]=a1.x; As[ak+5][ar]=a1.y; As[ak+6][ar]=a1.z; As[ak+7][ar]=a1.w;
    Bs[br][bc+0]=b0.x; Bs[br][bc+1]=b0.y; Bs[br][bc+2]=b0.z; Bs[br][bc+3]=b0.w;
    Bs[br][bc+4]=b1.x; Bs[br][bc+5]=b1.y; Bs[br][bc+6]=b1.z; Bs[br][bc+7]=b1.w;
    __syncthreads();

    #pragma unroll
    for (int kk = 0; kk < BK; kk++){
      float a[8], b[TN];
      #pragma unroll
      for (int i = 0; i < 8; i++) a[i] = As[kk][ty * 8 + i];
      #pragma unroll
      for (int j = 0; j < TN; j++) b[j] = Bs[kk][tx * TN + j];
      #pragma unroll
      for (int i = 0; i < 8; i++)
        #pragma unroll
        for (int j = 0; j < TN; j++)
          acc[i][j] = fmaf(a[i], b[j], acc[i][j]);
    }
  }

  const int nb = tx * TN;
  #pragma unroll
  for (int i = 0; i < 8; i++){
    int m = row0 + ty * 8 + i;
    if (m >= M) continue;
    union { int4 v4; u16 h[8]; } pk;
    #pragma unroll
    for (int j = 0; j < TN; j++) pk.h[j] = f2bf(acc[i][j]);
    *(int4*)(out + (size_t)m * BN + nb) = pk.v4;
  }
}

// ---------------- GEMM2: [M x 128](bf16 h1, relu-on-load for rows<n_s) @ W1[128 x 64](f32) -> f32 d_out ----
__global__ __launch_bounds__(256) void k_gemm2(
    const u16* __restrict__ h1, const float* __restrict__ W,
    int M, int n_s, float* __restrict__ out)
{
  constexpr int BM = 128, BK = 16, BN = 64, TN = 4, K = D_H;
  __shared__ float As[BK][BM + 4];
  __shared__ float Bs[BK][BN + 4];

  const int t  = threadIdx.x;
  const int tx = t & 15;
  const int ty = t >> 4;
  const int row0 = blockIdx.x * BM;

  float acc[8][TN];
  #pragma unroll
  for (int i = 0; i < 8; i++)
    #pragma unroll
    for (int j = 0; j < TN; j++) acc[i][j] = 0.f;

  const int ar = t >> 1;
  const int ak = (t & 1) * 8;
  const int r  = row0 + ar;
  const bool relu_a = (r < n_s);

  const int br = t >> 4;           // 0..15 (4 W elems per thread)
  const int bc = (t & 15) * 4;

  for (int k0 = 0; k0 < K; k0 += BK){
    union { int4 v; u16 h[8]; } ald;
    if (r < M) ald.v = *(const int4*)(h1 + (size_t)r * K + k0 + ak);
    else       ald.v = make_int4(0,0,0,0);
    float4 b0 = *(const float4*)(W + (size_t)(br + k0) * BN + bc);

    __syncthreads();
    #pragma unroll
    for (int j = 0; j < 8; j++){
      float v = bf2f(ald.h[j]);
      if (relu_a) v = fmaxf(v, 0.f);
      As[ak + j][ar] = v;
    }
    Bs[br][bc+0]=b0.x; Bs[br][bc+1]=b0.y; Bs[br][bc+2]=b0.z; Bs[br][bc+3]=b0.w;
    __syncthreads();

    #pragma unroll
    for (int kk = 0; kk < BK; kk++){
      float a[8], b[TN];
      #pragma unroll
      for (int i = 0; i < 8; i++) a[i] = As[kk][ty * 8 + i];
      #pragma unroll
      for (int j = 0; j < TN; j++) b[j] = Bs[kk][tx * TN + j];
      #pragma unroll
      for (int i = 0; i < 8; i++)
        #pragma unroll
        for (int j = 0; j < TN; j++)
          acc[i][j] = fmaf(a[i], b[j], acc[i][j]);
    }
  }

  const int nb = tx * TN;
  #pragma unroll
  for (int i = 0; i < 8; i++){
    int m = row0 + ty * 8 + i;
    if (m >= M) continue;
    float4 o = make_float4(acc[i][0], acc[i][1], acc[i][2], acc[i][3]);
    *(float4*)(out + (size_t)m * BN + nb) = o;
  }
}

// ---------------- layer-1 aggregation: one wave per dst node, 128 bf16 feats, in place ----
__global__ __launch_bounds__(256) void k_agg1(
    const int* __restrict__ off, const int* __restrict__ deg,
    const int* __restrict__ csr, const float* __restrict__ dinv,
    u16* __restrict__ h1, int n_s, int n_t)
{
  int w    = (blockIdx.x * 256 + threadIdx.x) >> 6;
  int lane = threadIdx.x & 63;
  if (w >= n_t) return;
  int start = off[w];
  int n     = deg[w];

  float s0 = 0.f, s1 = 0.f, s2 = 0.f, s3 = 0.f;
  int i = 0;
  for (; i + 2 <= n; i += 2){
    int sa = csr[start + i];
    int sb = csr[start + i + 1];
    u32 da = *(const u32*)(h1 + (size_t)sa * D_H + lane * 2);
    u32 db = *(const u32*)(h1 + (size_t)sb * D_H + lane * 2);
    s0 += bf2f((u16)da); s1 += bf2f((u16)(da >> 16));
    s2 += bf2f((u16)db); s3 += bf2f((u16)(db >> 16));
  }
  if (i < n){
    int sa = csr[start + i];
    u32 da = *(const u32*)(h1 + (size_t)sa * D_H + lane * 2);
    s0 += bf2f((u16)da); s1 += bf2f((u16)(da >> 16));
  }
  s0 += s2; s1 += s3;

  float di  = dinv[w];
  float di2 = di * di;
  u32* selfp = (u32*)(h1 + (size_t)(n_s + w) * D_H + lane * 2);
  u32 ht = *selfp;
  float v0 = fmaxf(di * s0 + di2 * bf2f((u16)ht), 0.f);
  float v1 = fmaxf(di * s1 + di2 * bf2f((u16)(ht >> 16)), 0.f);
  *selfp = (u32)f2bf(v0) | ((u32)f2bf(v1) << 16);
}

// ---------------- layer-2 aggregation: one wave per dst node, 64 f32 feats, in place ----
__global__ __launch_bounds__(256) void k_agg2(
    const int* __restrict__ off, const int* __restrict__ deg,
    const int* __restrict__ csr, const float* __restrict__ dinv,
    float* __restrict__ y, int n_s, int n_t)
{
  int w    = (blockIdx.x * 256 + threadIdx.x) >> 6;
  int lane = threadIdx.x & 63;
  if (w >= n_t) return;
  int start = off[w];
  int n     = deg[w];

  float s0 = 0.f, s1 = 0.f;
  int i = 0;
  for (; i + 2 <= n; i += 2){
    int sa = csr[start + i];
    int sb = csr[start + i + 1];
    s0 += y[(size_t)sa * D_OUT + lane];
    s1 += y[(size_t)sb * D_OUT + lane];
  }
  if (i < n){
    int sa = csr[start + i];
    s0 += y[(size_t)sa * D_OUT + lane];
  }
  s0 += s1;

  float di = dinv[w];
  float* selfp = y + (size_t)(n_s + w) * D_OUT + lane;
  *selfp = di * s0 + di * di * (*selfp);
}

static inline size_t alup(size_t x){ return (x + 255) & ~(size_t)255; }

extern "C" void kernel_launch(void* const* d_in, const int* in_sizes, int n_in,
                              void* d_out, int out_size, void* d_ws, size_t ws_size,
                              hipStream_t stream)
{
  const int*   ei = (const int*)d_in[0];
  const float* xs = (const float*)d_in[1];
  const float* xt = (const float*)d_in[2];
  const float* W0 = (const float*)d_in[3];
  const float* W1 = (const float*)d_in[4];
  const int E   = in_sizes[0] / 2;
  const int n_s = in_sizes[1] / D_IN;
  const int n_t = in_sizes[2] / D_IN;
  const int M   = n_s + n_t;
  const int* src = ei;       // edge_index row 0
  const int* dst = ei + E;   // edge_index row 1 (0-based target index)
  const int nb_t = (n_t + 255) / 256;

  // workspace layout (~29 MB)
  char* p = (char*)d_ws;
  int*   deg    = (int*)p;    p += alup((size_t)n_t * 4);
  int*   off    = (int*)p;    p += alup((size_t)n_t * 4);
  int*   cursor = (int*)p;    p += alup((size_t)n_t * 4);
  float* dinv   = (float*)p;  p += alup((size_t)n_t * 4);
  int*   bsum   = (int*)p;    p += alup((size_t)nb_t * 4);
  int*   csr    = (int*)p;    p += alup((size_t)E * 4);
  u16*   h1     = (u16*)p;    p += alup((size_t)M * D_H * 2);

  k_zero  <<<nb_t, 256, 0, stream>>>(deg, n_t);
  k_deg   <<<(E + 255) / 256, 256, 0, stream>>>(dst, E, deg);
  k_bsum  <<<nb_t, 256, 0, stream>>>(deg, n_t, bsum);
  k_bscan <<<1, 256, 0, stream>>>(bsum, nb_t);
  k_off   <<<nb_t, 256, 0, stream>>>(deg, n_t, bsum, off, cursor, dinv);
  k_fill  <<<(E + 255) / 256, 256, 0, stream>>>(src, dst, E, cursor, csr);

  // layer 1: h1 = X @ W0 (f32 in, bf16 out, raw all rows)
  k_gemm1<<<(M + 127) / 128, 256, 0, stream>>>(xs, xt, W0, M, n_s, h1);
  // target rows of h1 <- relu(dinv*sum_in(h1_s) + dinv^2*h1_t), in place
  k_agg1<<<(n_t + 3) / 4, 256, 0, stream>>>(off, deg, csr, dinv, h1, n_s, n_t);

  // layer 2: y = relu_on_load(h1) @ W1 -> f32 d_out (all rows)
  k_gemm2<<<(M + 127) / 128, 256, 0, stream>>>(h1, W1, M, n_s, (float*)d_out);
  // target rows of d_out <- dinv*sum_in(y_s) + dinv^2*h2_t, in place
  k_agg2<<<(n_t + 3) / 4, 256, 0, stream>>>(off, deg, csr, dinv,
                                            (float*)d_out, n_s, n_t);
}

// Round 6
// 310.574 us; speedup vs baseline: 1.2415x; 1.2415x over previous
//
#include <hip/hip_runtime.h>
#include <cstdint>
#include <cstddef>

typedef unsigned short u16;
typedef unsigned int   u32;
typedef __attribute__((ext_vector_type(8))) short bf16x8;
typedef __attribute__((ext_vector_type(4))) float f32x4;

#define D_IN  256
#define D_H   128
#define D_OUT 64
#define LSTR  72   // LDS row stride (u16 elems): non-pow2 -> conflict-free-ish

__device__ __forceinline__ float bf2f(u16 u){
  union { u32 i; float f; } v; v.i = ((u32)u) << 16; return v.f;
}
__device__ __forceinline__ u16 f2bf(float f){
  union { float f; u32 i; } v; v.f = f;
  u32 r = (v.i + 0x7fffu + ((v.i >> 16) & 1u)) >> 16;
  return (u16)r;
}

// ---------------- graph prep ----------------
__global__ void k_zero(int* __restrict__ p, int n){
  int i = blockIdx.x * 256 + threadIdx.x;
  if (i < n) p[i] = 0;
}

__global__ void k_deg(const int* __restrict__ dst, int E, int* __restrict__ deg){
  int e = blockIdx.x * 256 + threadIdx.x;
  if (e < E) atomicAdd(&deg[dst[e]], 1);
}

__global__ __launch_bounds__(256) void k_bsum(const int* __restrict__ deg, int N,
                                              int* __restrict__ bsum){
  __shared__ int s[256];
  int tid = threadIdx.x;
  int i = blockIdx.x * 256 + tid;
  s[tid] = (i < N) ? deg[i] : 0;
  __syncthreads();
  for (int o = 128; o > 0; o >>= 1){
    if (tid < o) s[tid] += s[tid + o];
    __syncthreads();
  }
  if (tid == 0) bsum[blockIdx.x] = s[0];
}

__global__ __launch_bounds__(256) void k_bscan(int* __restrict__ bsum, int nb){
  __shared__ int s[256];
  int tid = threadIdx.x;
  int v = (tid < nb) ? bsum[tid] : 0;
  s[tid] = v;
  __syncthreads();
  for (int o = 1; o < 256; o <<= 1){
    int t = (tid >= o) ? s[tid - o] : 0;
    __syncthreads();
    s[tid] += t;
    __syncthreads();
  }
  if (tid < nb) bsum[tid] = s[tid] - v;
}

__global__ __launch_bounds__(256) void k_off(const int* __restrict__ deg, int N,
                                             const int* __restrict__ bsum,
                                             int* __restrict__ off, int* __restrict__ cursor,
                                             float* __restrict__ dinv){
  __shared__ int s[256];
  int tid = threadIdx.x;
  int i = blockIdx.x * 256 + tid;
  int v = (i < N) ? deg[i] : 0;
  s[tid] = v;
  __syncthreads();
  for (int o = 1; o < 256; o <<= 1){
    int t = (tid >= o) ? s[tid - o] : 0;
    __syncthreads();
    s[tid] += t;
    __syncthreads();
  }
  if (i < N){
    int excl = s[tid] - v + bsum[blockIdx.x];
    off[i] = excl;
    cursor[i] = excl;
    dinv[i] = rsqrtf((float)v + 1.0f);
  }
}

__global__ void k_fill(const int* __restrict__ src, const int* __restrict__ dst,
                       int E, int* __restrict__ cursor, int* __restrict__ csr){
  int e = blockIdx.x * 256 + threadIdx.x;
  if (e < E){
    int d = dst[e];
    int p = atomicAdd(&cursor[d], 1);
    csr[p] = src[e];
  }
}

// ---------------- weight prep: W0[256][128]f32 -> W0t[128][256]bf16 ;
//                  W1[128][64]f32 -> W1t[64][128]bf16 ----------------
__global__ void k_wprep(const float* __restrict__ W0, const float* __restrict__ W1,
                        u16* __restrict__ W0t, u16* __restrict__ W1t){
  int i = blockIdx.x * 256 + threadIdx.x;
  if (i < 128 * 256){
    int n = i >> 8, k = i & 255;
    W0t[i] = f2bf(W0[(size_t)k * 128 + n]);
  } else if (i < 128 * 256 + 64 * 128){
    int j = i - 128 * 256;
    int n = j >> 7, k = j & 127;
    W1t[j] = f2bf(W1[(size_t)k * 64 + n]);
  }
}

// ---------------- GEMM1 (MFMA): [M x 256] f32 @ W0t -> h1[M x 128] bf16 ----------------
// Tile 128x128, BK=64. 4 waves in 2x2; each wave 64x64 via 4x4 mfma_16x16x32.
__global__ __launch_bounds__(256) void k_gemm1(
    const float* __restrict__ Xs, const float* __restrict__ Xt,
    const u16* __restrict__ W0t, int M, int n_s,
    u16* __restrict__ out)
{
  __shared__ u16 As[128 * LSTR];
  __shared__ u16 Bs[128 * LSTR];
  const int t    = threadIdx.x;
  const int wave = t >> 6, lane = t & 63;
  const int wm   = (wave >> 1) * 64, wn = (wave & 1) * 64;
  const int lm   = lane & 15, quad = lane >> 4;
  const int row0 = blockIdx.x * 128;

  f32x4 acc[4][4];
  const f32x4 z = {0.f, 0.f, 0.f, 0.f};
  #pragma unroll
  for (int i = 0; i < 4; i++)
    #pragma unroll
    for (int j = 0; j < 4; j++) acc[i][j] = z;

  // staging: thread t handles row ar, k-half kh (32 elems)
  const int ar = t >> 1;
  const int kh = (t & 1) * 32;
  const int r  = row0 + ar;
  const float* xp = nullptr;
  if (r < M) xp = (r < n_s) ? (Xs + (size_t)r * D_IN) : (Xt + (size_t)(r - n_s) * D_IN);
  const u16* wrow = W0t + (size_t)ar * D_IN + kh;

  for (int k0 = 0; k0 < D_IN; k0 += 64){
    u16 abuf[32];
    if (xp){
      #pragma unroll
      for (int j = 0; j < 8; j++){
        float4 v = *(const float4*)(xp + k0 + kh + j * 4);
        abuf[j*4+0] = f2bf(v.x); abuf[j*4+1] = f2bf(v.y);
        abuf[j*4+2] = f2bf(v.z); abuf[j*4+3] = f2bf(v.w);
      }
    } else {
      #pragma unroll
      for (int j = 0; j < 32; j++) abuf[j] = 0;
    }
    int4 b0 = *(const int4*)(wrow + k0);
    int4 b1 = *(const int4*)(wrow + k0 + 8);
    int4 b2 = *(const int4*)(wrow + k0 + 16);
    int4 b3 = *(const int4*)(wrow + k0 + 24);

    __syncthreads();
    {
      u16* ap = &As[ar * LSTR + kh];
      *(int4*)(ap +  0) = *(int4*)&abuf[0];
      *(int4*)(ap +  8) = *(int4*)&abuf[8];
      *(int4*)(ap + 16) = *(int4*)&abuf[16];
      *(int4*)(ap + 24) = *(int4*)&abuf[24];
      u16* bp = &Bs[ar * LSTR + kh];
      *(int4*)(bp +  0) = b0;
      *(int4*)(bp +  8) = b1;
      *(int4*)(bp + 16) = b2;
      *(int4*)(bp + 24) = b3;
    }
    __syncthreads();

    #pragma unroll
    for (int kk = 0; kk < 64; kk += 32){
      bf16x8 af[4], bf[4];
      #pragma unroll
      for (int i = 0; i < 4; i++)
        af[i] = *(const bf16x8*)&As[(wm + i*16 + lm) * LSTR + kk + quad*8];
      #pragma unroll
      for (int i = 0; i < 4; i++)
        bf[i] = *(const bf16x8*)&Bs[(wn + i*16 + lm) * LSTR + kk + quad*8];
      #pragma unroll
      for (int mi = 0; mi < 4; mi++)
        #pragma unroll
        for (int ni = 0; ni < 4; ni++)
          acc[mi][ni] = __builtin_amdgcn_mfma_f32_16x16x32_bf16(
              af[mi], bf[ni], acc[mi][ni], 0, 0, 0);
    }
  }

  // epilogue: C[row=quad*4+reg][col=lm] per 16x16; bf16 out
  #pragma unroll
  for (int mi = 0; mi < 4; mi++){
    int rbase = row0 + wm + mi * 16 + quad * 4;
    #pragma unroll
    for (int rr = 0; rr < 4; rr++){
      int m = rbase + rr;
      if (m >= M) continue;
      u16* op = out + (size_t)m * D_H + wn + lm;
      #pragma unroll
      for (int ni = 0; ni < 4; ni++)
        op[ni * 16] = f2bf(acc[mi][ni][rr]);
    }
  }
}

// ---------------- GEMM2 (MFMA): relu(h1)[M x 128] bf16 @ W1t -> d_out[M x 64] f32 ----------------
// Tile 128x64, BK=64. 4 waves stacked in m; each wave 32x64 via 2x4 mfma.
__global__ __launch_bounds__(256) void k_gemm2(
    const u16* __restrict__ h1, const u16* __restrict__ W1t,
    int M, float* __restrict__ out)
{
  __shared__ u16 As[128 * LSTR];
  __shared__ u16 Bs[64 * LSTR];
  const int t    = threadIdx.x;
  const int wave = t >> 6, lane = t & 63;
  const int wm   = wave * 32;
  const int lm   = lane & 15, quad = lane >> 4;
  const int row0 = blockIdx.x * 128;

  f32x4 acc[2][4];
  const f32x4 z = {0.f, 0.f, 0.f, 0.f};
  #pragma unroll
  for (int i = 0; i < 2; i++)
    #pragma unroll
    for (int j = 0; j < 4; j++) acc[i][j] = z;

  const int ar = t >> 1;
  const int kh = (t & 1) * 32;
  const int r  = row0 + ar;
  // B staging: thread t -> n-row t>>2 (0..63), k-quarter (t&3)*16
  const int bn = t >> 2;
  const int bk = (t & 3) * 16;

  for (int k0 = 0; k0 < D_H; k0 += 64){
    // A: 32 bf16 with unconditional relu (idempotent for target rows)
    u16 abuf[32];
    if (r < M){
      const u16* hp = h1 + (size_t)r * D_H + k0 + kh;
      #pragma unroll
      for (int j = 0; j < 4; j++){
        int4 v = *(const int4*)(hp + j * 8);
        u16* hh = (u16*)&v;
        #pragma unroll
        for (int q = 0; q < 8; q++)
          abuf[j*8+q] = (hh[q] & 0x8000u) ? (u16)0 : hh[q];
      }
    } else {
      #pragma unroll
      for (int j = 0; j < 32; j++) abuf[j] = 0;
    }
    int4 w0 = *(const int4*)(W1t + (size_t)bn * D_H + k0 + bk);
    int4 w1 = *(const int4*)(W1t + (size_t)bn * D_H + k0 + bk + 8);

    __syncthreads();
    {
      u16* ap = &As[ar * LSTR + kh];
      *(int4*)(ap +  0) = *(int4*)&abuf[0];
      *(int4*)(ap +  8) = *(int4*)&abuf[8];
      *(int4*)(ap + 16) = *(int4*)&abuf[16];
      *(int4*)(ap + 24) = *(int4*)&abuf[24];
      u16* bp = &Bs[bn * LSTR + bk];
      *(int4*)(bp + 0) = w0;
      *(int4*)(bp + 8) = w1;
    }
    __syncthreads();

    #pragma unroll
    for (int kk = 0; kk < 64; kk += 32){
      bf16x8 af[2], bf[4];
      #pragma unroll
      for (int i = 0; i < 2; i++)
        af[i] = *(const bf16x8*)&As[(wm + i*16 + lm) * LSTR + kk + quad*8];
      #pragma unroll
      for (int i = 0; i < 4; i++)
        bf[i] = *(const bf16x8*)&Bs[(i*16 + lm) * LSTR + kk + quad*8];
      #pragma unroll
      for (int mi = 0; mi < 2; mi++)
        #pragma unroll
        for (int ni = 0; ni < 4; ni++)
          acc[mi][ni] = __builtin_amdgcn_mfma_f32_16x16x32_bf16(
              af[mi], bf[ni], acc[mi][ni], 0, 0, 0);
    }
  }

  #pragma unroll
  for (int mi = 0; mi < 2; mi++){
    int rbase = row0 + wm + mi * 16 + quad * 4;
    #pragma unroll
    for (int rr = 0; rr < 4; rr++){
      int m = rbase + rr;
      if (m >= M) continue;
      float* op = out + (size_t)m * D_OUT + lm;
      #pragma unroll
      for (int ni = 0; ni < 4; ni++)
        op[ni * 16] = acc[mi][ni][rr];
    }
  }
}

// ---------------- layer-1 aggregation: one wave per dst node, 128 bf16 feats, in place ----
__global__ __launch_bounds__(256) void k_agg1(
    const int* __restrict__ off, const int* __restrict__ deg,
    const int* __restrict__ csr, const float* __restrict__ dinv,
    u16* __restrict__ h1, int n_s, int n_t)
{
  int w    = (blockIdx.x * 256 + threadIdx.x) >> 6;
  int lane = threadIdx.x & 63;
  if (w >= n_t) return;
  int start = off[w];
  int n     = deg[w];

  float s0 = 0.f, s1 = 0.f, s2 = 0.f, s3 = 0.f;
  int i = 0;
  for (; i + 2 <= n; i += 2){
    int sa = csr[start + i];
    int sb = csr[start + i + 1];
    u32 da = *(const u32*)(h1 + (size_t)sa * D_H + lane * 2);
    u32 db = *(const u32*)(h1 + (size_t)sb * D_H + lane * 2);
    s0 += bf2f((u16)da); s1 += bf2f((u16)(da >> 16));
    s2 += bf2f((u16)db); s3 += bf2f((u16)(db >> 16));
  }
  if (i < n){
    int sa = csr[start + i];
    u32 da = *(const u32*)(h1 + (size_t)sa * D_H + lane * 2);
    s0 += bf2f((u16)da); s1 += bf2f((u16)(da >> 16));
  }
  s0 += s2; s1 += s3;

  float di  = dinv[w];
  float di2 = di * di;
  u32* selfp = (u32*)(h1 + (size_t)(n_s + w) * D_H + lane * 2);
  u32 ht = *selfp;
  float v0 = fmaxf(di * s0 + di2 * bf2f((u16)ht), 0.f);
  float v1 = fmaxf(di * s1 + di2 * bf2f((u16)(ht >> 16)), 0.f);
  *selfp = (u32)f2bf(v0) | ((u32)f2bf(v1) << 16);
}

// ---------------- layer-2 aggregation: one wave per dst node, 64 f32 feats, in place ----
__global__ __launch_bounds__(256) void k_agg2(
    const int* __restrict__ off, const int* __restrict__ deg,
    const int* __restrict__ csr, const float* __restrict__ dinv,
    float* __restrict__ y, int n_s, int n_t)
{
  int w    = (blockIdx.x * 256 + threadIdx.x) >> 6;
  int lane = threadIdx.x & 63;
  if (w >= n_t) return;
  int start = off[w];
  int n     = deg[w];

  float s0 = 0.f, s1 = 0.f;
  int i = 0;
  for (; i + 2 <= n; i += 2){
    int sa = csr[start + i];
    int sb = csr[start + i + 1];
    s0 += y[(size_t)sa * D_OUT + lane];
    s1 += y[(size_t)sb * D_OUT + lane];
  }
  if (i < n){
    int sa = csr[start + i];
    s0 += y[(size_t)sa * D_OUT + lane];
  }
  s0 += s1;

  float di = dinv[w];
  float* selfp = y + (size_t)(n_s + w) * D_OUT + lane;
  *selfp = di * s0 + di * di * (*selfp);
}

static inline size_t alup(size_t x){ return (x + 255) & ~(size_t)255; }

extern "C" void kernel_launch(void* const* d_in, const int* in_sizes, int n_in,
                              void* d_out, int out_size, void* d_ws, size_t ws_size,
                              hipStream_t stream)
{
  const int*   ei = (const int*)d_in[0];
  const float* xs = (const float*)d_in[1];
  const float* xt = (const float*)d_in[2];
  const float* W0 = (const float*)d_in[3];
  const float* W1 = (const float*)d_in[4];
  const int E   = in_sizes[0] / 2;
  const int n_s = in_sizes[1] / D_IN;
  const int n_t = in_sizes[2] / D_IN;
  const int M   = n_s + n_t;
  const int* src = ei;       // edge_index row 0
  const int* dst = ei + E;   // edge_index row 1 (0-based target index)
  const int nb_t = (n_t + 255) / 256;

  // workspace layout (~29 MB)
  char* p = (char*)d_ws;
  int*   deg    = (int*)p;    p += alup((size_t)n_t * 4);
  int*   off    = (int*)p;    p += alup((size_t)n_t * 4);
  int*   cursor = (int*)p;    p += alup((size_t)n_t * 4);
  float* dinv   = (float*)p;  p += alup((size_t)n_t * 4);
  int*   bsum   = (int*)p;    p += alup((size_t)nb_t * 4);
  int*   csr    = (int*)p;    p += alup((size_t)E * 4);
  u16*   W0t    = (u16*)p;    p += alup((size_t)D_H * D_IN * 2);
  u16*   W1t    = (u16*)p;    p += alup((size_t)D_OUT * D_H * 2);
  u16*   h1     = (u16*)p;    p += alup((size_t)M * D_H * 2);

  k_wprep <<<(128*256 + 64*128 + 255) / 256, 256, 0, stream>>>(W0, W1, W0t, W1t);
  k_zero  <<<nb_t, 256, 0, stream>>>(deg, n_t);
  k_deg   <<<(E + 255) / 256, 256, 0, stream>>>(dst, E, deg);
  k_bsum  <<<nb_t, 256, 0, stream>>>(deg, n_t, bsum);
  k_bscan <<<1, 256, 0, stream>>>(bsum, nb_t);
  k_off   <<<nb_t, 256, 0, stream>>>(deg, n_t, bsum, off, cursor, dinv);
  k_fill  <<<(E + 255) / 256, 256, 0, stream>>>(src, dst, E, cursor, csr);

  // layer 1: h1 = X @ W0 (MFMA, f32 in, bf16 out, raw all rows)
  k_gemm1<<<(M + 127) / 128, 256, 0, stream>>>(xs, xt, W0t, M, n_s, h1);
  // target rows of h1 <- relu(dinv*sum_in(h1_s) + dinv^2*h1_t), in place
  k_agg1<<<(n_t + 3) / 4, 256, 0, stream>>>(off, deg, csr, dinv, h1, n_s, n_t);

  // layer 2: y = relu(h1) @ W1 (MFMA) -> f32 d_out (all rows)
  k_gemm2<<<(M + 127) / 128, 256, 0, stream>>>(h1, W1t, M, (float*)d_out);
  // target rows of d_out <- dinv*sum_in(y_s) + dinv^2*h2_t, in place
  k_agg2<<<(n_t + 3) / 4, 256, 0, stream>>>(off, deg, csr, dinv,
                                            (float*)d_out, n_s, n_t);
}

// Round 7
// 284.992 us; speedup vs baseline: 1.3530x; 1.0898x over previous
//
#include <hip/hip_runtime.h>
#include <cstdint>
#include <cstddef>

typedef unsigned short u16;
typedef unsigned int   u32;
typedef __attribute__((ext_vector_type(8))) short bf16x8;
typedef __attribute__((ext_vector_type(4))) float f32x4;

#define D_IN  256
#define D_H   128
#define D_OUT 64
#define LSTR  72   // LDS row stride (u16): non-pow2 -> conflict-light

__device__ __forceinline__ float bf2f(u16 u){
  union { u32 i; float f; } v; v.i = ((u32)u) << 16; return v.f;
}
__device__ __forceinline__ u16 f2bf(float f){
  union { float f; u32 i; } v; v.f = f;
  u32 r = (v.i + 0x7fffu + ((v.i >> 16) & 1u)) >> 16;
  return (u16)r;
}

// ---------------- weight prep + deg zero (fused) ----------------
__global__ void k_wprep(const float* __restrict__ W0, const float* __restrict__ W1,
                        u16* __restrict__ W0t, u16* __restrict__ W1t,
                        int* __restrict__ deg, int n_t){
  int i = blockIdx.x * 256 + threadIdx.x;
  if (i < 128 * 256){
    int n = i >> 8, k = i & 255;
    W0t[i] = f2bf(W0[(size_t)k * 128 + n]);
  } else if (i < 128 * 256 + 64 * 128){
    int j = i - 128 * 256;
    int n = j >> 7, k = j & 127;
    W1t[j] = f2bf(W1[(size_t)k * 64 + n]);
  } else if (i - (128 * 256 + 64 * 128) < n_t){
    deg[i - (128 * 256 + 64 * 128)] = 0;
  }
}

// ---------------- graph prep ----------------
__global__ void k_deg(const int* __restrict__ dst, int E, int* __restrict__ deg){
  int e = blockIdx.x * 256 + threadIdx.x;
  if (e < E) atomicAdd(&deg[dst[e]], 1);
}

__global__ __launch_bounds__(256) void k_bsum(const int* __restrict__ deg, int N,
                                              int* __restrict__ bsum){
  __shared__ int s[256];
  int tid = threadIdx.x;
  int i = blockIdx.x * 256 + tid;
  s[tid] = (i < N) ? deg[i] : 0;
  __syncthreads();
  for (int o = 128; o > 0; o >>= 1){
    if (tid < o) s[tid] += s[tid + o];
    __syncthreads();
  }
  if (tid == 0) bsum[blockIdx.x] = s[0];
}

__global__ __launch_bounds__(256) void k_bscan(int* __restrict__ bsum, int nb){
  __shared__ int s[256];
  int tid = threadIdx.x;
  int v = (tid < nb) ? bsum[tid] : 0;
  s[tid] = v;
  __syncthreads();
  for (int o = 1; o < 256; o <<= 1){
    int t = (tid >= o) ? s[tid - o] : 0;
    __syncthreads();
    s[tid] += t;
    __syncthreads();
  }
  if (tid < nb) bsum[tid] = s[tid] - v;
}

__global__ __launch_bounds__(256) void k_off(const int* __restrict__ deg, int N,
                                             const int* __restrict__ bsum,
                                             int* __restrict__ off, int* __restrict__ cursor,
                                             float* __restrict__ dinv){
  __shared__ int s[256];
  int tid = threadIdx.x;
  int i = blockIdx.x * 256 + tid;
  int v = (i < N) ? deg[i] : 0;
  s[tid] = v;
  __syncthreads();
  for (int o = 1; o < 256; o <<= 1){
    int t = (tid >= o) ? s[tid - o] : 0;
    __syncthreads();
    s[tid] += t;
    __syncthreads();
  }
  if (i < N){
    int excl = s[tid] - v + bsum[blockIdx.x];
    off[i] = excl;
    cursor[i] = excl;
    dinv[i] = rsqrtf((float)v + 1.0f);
  }
}

__global__ void k_fill(const int* __restrict__ src, const int* __restrict__ dst,
                       int E, int* __restrict__ cursor, int* __restrict__ csr){
  int e = blockIdx.x * 256 + threadIdx.x;
  if (e < E){
    int d = dst[e];
    int p = atomicAdd(&cursor[d], 1);
    csr[p] = src[e];
  }
}

// ---------------- GEMM1 (MFMA, sw-pipelined): X f32 @ W0t -> h1 bf16 ----------------
__global__ __launch_bounds__(256) void k_gemm1(
    const float* __restrict__ Xs, const float* __restrict__ Xt,
    const u16* __restrict__ W0t, int M, int n_s,
    u16* __restrict__ out)
{
  __shared__ u16 As[128 * LSTR];
  __shared__ u16 Bs[128 * LSTR];
  const int t    = threadIdx.x;
  const int wave = t >> 6, lane = t & 63;
  const int wm   = (wave >> 1) * 64, wn = (wave & 1) * 64;
  const int lm   = lane & 15, quad = lane >> 4;
  const int row0 = blockIdx.x * 128;

  f32x4 acc[4][4];
  const f32x4 z = {0.f, 0.f, 0.f, 0.f};
  #pragma unroll
  for (int i = 0; i < 4; i++)
    #pragma unroll
    for (int j = 0; j < 4; j++) acc[i][j] = z;

  const int ar = t >> 1;
  const int kh = (t & 1) * 32;
  const int r  = row0 + ar;
  const float* xp = nullptr;
  if (r < M) xp = (r < n_s) ? (Xs + (size_t)r * D_IN) : (Xt + (size_t)(r - n_s) * D_IN);
  const u16* wrow = W0t + (size_t)ar * D_IN + kh;

  float4 a4[8];
  int4   b4[4];
  // prefetch k0 = 0
  if (xp){
    #pragma unroll
    for (int j = 0; j < 8; j++) a4[j] = *(const float4*)(xp + kh + j * 4);
  } else {
    float4 zz = make_float4(0,0,0,0);
    #pragma unroll
    for (int j = 0; j < 8; j++) a4[j] = zz;
  }
  #pragma unroll
  for (int j = 0; j < 4; j++) b4[j] = *(const int4*)(wrow + j * 8);

  for (int k0 = 0; k0 < D_IN; k0 += 64){
    __syncthreads();
    {
      u16 abuf[32];
      #pragma unroll
      for (int j = 0; j < 8; j++){
        abuf[j*4+0] = f2bf(a4[j].x); abuf[j*4+1] = f2bf(a4[j].y);
        abuf[j*4+2] = f2bf(a4[j].z); abuf[j*4+3] = f2bf(a4[j].w);
      }
      u16* ap = &As[ar * LSTR + kh];
      *(int4*)(ap +  0) = *(int4*)&abuf[0];
      *(int4*)(ap +  8) = *(int4*)&abuf[8];
      *(int4*)(ap + 16) = *(int4*)&abuf[16];
      *(int4*)(ap + 24) = *(int4*)&abuf[24];
      u16* bp = &Bs[ar * LSTR + kh];
      *(int4*)(bp +  0) = b4[0];
      *(int4*)(bp +  8) = b4[1];
      *(int4*)(bp + 16) = b4[2];
      *(int4*)(bp + 24) = b4[3];
    }
    __syncthreads();

    // prefetch next k-tile: overlaps with MFMA below
    if (k0 + 64 < D_IN){
      if (xp){
        #pragma unroll
        for (int j = 0; j < 8; j++) a4[j] = *(const float4*)(xp + k0 + 64 + kh + j * 4);
      }
      #pragma unroll
      for (int j = 0; j < 4; j++) b4[j] = *(const int4*)(wrow + k0 + 64 + j * 8);
    }

    #pragma unroll
    for (int kk = 0; kk < 64; kk += 32){
      bf16x8 af[4], bfr[4];
      #pragma unroll
      for (int i = 0; i < 4; i++)
        af[i] = *(const bf16x8*)&As[(wm + i*16 + lm) * LSTR + kk + quad*8];
      #pragma unroll
      for (int i = 0; i < 4; i++)
        bfr[i] = *(const bf16x8*)&Bs[(wn + i*16 + lm) * LSTR + kk + quad*8];
      #pragma unroll
      for (int mi = 0; mi < 4; mi++)
        #pragma unroll
        for (int ni = 0; ni < 4; ni++)
          acc[mi][ni] = __builtin_amdgcn_mfma_f32_16x16x32_bf16(
              af[mi], bfr[ni], acc[mi][ni], 0, 0, 0);
    }
  }

  #pragma unroll
  for (int mi = 0; mi < 4; mi++){
    int rbase = row0 + wm + mi * 16 + quad * 4;
    #pragma unroll
    for (int rr = 0; rr < 4; rr++){
      int m = rbase + rr;
      if (m >= M) continue;
      u16* op = out + (size_t)m * D_H + wn + lm;
      #pragma unroll
      for (int ni = 0; ni < 4; ni++)
        op[ni * 16] = f2bf(acc[mi][ni][rr]);
    }
  }
}

// ---------------- fused aggregation: ONE gather pass for both layers ----------------
// Per target node w: s_raw = sum h1_s[src], s_rel = sum relu(h1_s[src]);
// z1_t = relu(di*s_raw + di^2*h1_t); u_t = di*s_rel + di^2*z1_t -> h1 target row in place.
__global__ __launch_bounds__(256) void k_aggf(
    const int* __restrict__ off, const int* __restrict__ deg,
    const int* __restrict__ csr, const float* __restrict__ dinv,
    u16* __restrict__ h1, int n_s, int n_t)
{
  int w    = (blockIdx.x * 256 + threadIdx.x) >> 6;
  int lane = threadIdx.x & 63;
  if (w >= n_t) return;
  int start = off[w];
  int n     = deg[w];

  float r0 = 0.f, r1 = 0.f, p0 = 0.f, p1 = 0.f;
  int i = 0;
  for (; i + 4 <= n; i += 4){
    int sa = csr[start + i];
    int sb = csr[start + i + 1];
    int sc = csr[start + i + 2];
    int sd = csr[start + i + 3];
    u32 da = *(const u32*)(h1 + (size_t)sa * D_H + lane * 2);
    u32 db = *(const u32*)(h1 + (size_t)sb * D_H + lane * 2);
    u32 dc = *(const u32*)(h1 + (size_t)sc * D_H + lane * 2);
    u32 dd = *(const u32*)(h1 + (size_t)sd * D_H + lane * 2);
    float va0 = bf2f((u16)da), va1 = bf2f((u16)(da >> 16));
    float vb0 = bf2f((u16)db), vb1 = bf2f((u16)(db >> 16));
    float vc0 = bf2f((u16)dc), vc1 = bf2f((u16)(dc >> 16));
    float vd0 = bf2f((u16)dd), vd1 = bf2f((u16)(dd >> 16));
    r0 += va0 + vb0 + vc0 + vd0;
    r1 += va1 + vb1 + vc1 + vd1;
    p0 += fmaxf(va0,0.f) + fmaxf(vb0,0.f) + fmaxf(vc0,0.f) + fmaxf(vd0,0.f);
    p1 += fmaxf(va1,0.f) + fmaxf(vb1,0.f) + fmaxf(vc1,0.f) + fmaxf(vd1,0.f);
  }
  for (; i < n; i++){
    int sa = csr[start + i];
    u32 da = *(const u32*)(h1 + (size_t)sa * D_H + lane * 2);
    float va0 = bf2f((u16)da), va1 = bf2f((u16)(da >> 16));
    r0 += va0; r1 += va1;
    p0 += fmaxf(va0,0.f); p1 += fmaxf(va1,0.f);
  }

  float di  = dinv[w];
  float di2 = di * di;
  u32* selfp = (u32*)(h1 + (size_t)(n_s + w) * D_H + lane * 2);
  u32 ht = *selfp;
  float z0 = fmaxf(di * r0 + di2 * bf2f((u16)ht), 0.f);
  float z1 = fmaxf(di * r1 + di2 * bf2f((u16)(ht >> 16)), 0.f);
  float u0 = di * p0 + di2 * z0;
  float u1 = di * p1 + di2 * z1;
  *selfp = (u32)f2bf(u0) | ((u32)f2bf(u1) << 16);
}

// ---------------- GEMM2 (MFMA, sw-pipelined): A @ W1t -> d_out f32 (final) ----------------
// A row r: r<n_s -> relu(h1_s) on load (z1_s); r>=n_s -> u_t raw (NO relu).
__global__ __launch_bounds__(256) void k_gemm2(
    const u16* __restrict__ h1, const u16* __restrict__ W1t,
    int M, int n_s, float* __restrict__ out)
{
  __shared__ u16 As[128 * LSTR];
  __shared__ u16 Bs[64 * LSTR];
  const int t    = threadIdx.x;
  const int wave = t >> 6, lane = t & 63;
  const int wm   = wave * 32;
  const int lm   = lane & 15, quad = lane >> 4;
  const int row0 = blockIdx.x * 128;

  f32x4 acc[2][4];
  const f32x4 z = {0.f, 0.f, 0.f, 0.f};
  #pragma unroll
  for (int i = 0; i < 2; i++)
    #pragma unroll
    for (int j = 0; j < 4; j++) acc[i][j] = z;

  const int ar = t >> 1;
  const int kh = (t & 1) * 32;
  const int r  = row0 + ar;
  const bool relu_a = (r < n_s);
  const int bn = t >> 2;
  const int bk = (t & 3) * 16;

  int4 a4[4], w4[2];
  if (r < M){
    const u16* hp = h1 + (size_t)r * D_H + kh;
    #pragma unroll
    for (int j = 0; j < 4; j++) a4[j] = *(const int4*)(hp + j * 8);
  } else {
    int4 zz = make_int4(0,0,0,0);
    #pragma unroll
    for (int j = 0; j < 4; j++) a4[j] = zz;
  }
  w4[0] = *(const int4*)(W1t + (size_t)bn * D_H + bk);
  w4[1] = *(const int4*)(W1t + (size_t)bn * D_H + bk + 8);

  for (int k0 = 0; k0 < D_H; k0 += 64){
    __syncthreads();
    {
      u16 abuf[32];
      #pragma unroll
      for (int j = 0; j < 4; j++){
        u16* hh = (u16*)&a4[j];
        #pragma unroll
        for (int q = 0; q < 8; q++){
          u16 v = hh[q];
          abuf[j*8+q] = (relu_a && (v & 0x8000u)) ? (u16)0 : v;
        }
      }
      u16* ap = &As[ar * LSTR + kh];
      *(int4*)(ap +  0) = *(int4*)&abuf[0];
      *(int4*)(ap +  8) = *(int4*)&abuf[8];
      *(int4*)(ap + 16) = *(int4*)&abuf[16];
      *(int4*)(ap + 24) = *(int4*)&abuf[24];
      u16* bp = &Bs[bn * LSTR + bk];
      *(int4*)(bp + 0) = w4[0];
      *(int4*)(bp + 8) = w4[1];
    }
    __syncthreads();

    if (k0 + 64 < D_H){
      if (r < M){
        const u16* hp = h1 + (size_t)r * D_H + k0 + 64 + kh;
        #pragma unroll
        for (int j = 0; j < 4; j++) a4[j] = *(const int4*)(hp + j * 8);
      }
      w4[0] = *(const int4*)(W1t + (size_t)bn * D_H + k0 + 64 + bk);
      w4[1] = *(const int4*)(W1t + (size_t)bn * D_H + k0 + 64 + bk + 8);
    }

    #pragma unroll
    for (int kk = 0; kk < 64; kk += 32){
      bf16x8 af[2], bfr[4];
      #pragma unroll
      for (int i = 0; i < 2; i++)
        af[i] = *(const bf16x8*)&As[(wm + i*16 + lm) * LSTR + kk + quad*8];
      #pragma unroll
      for (int i = 0; i < 4; i++)
        bfr[i] = *(const bf16x8*)&Bs[(i*16 + lm) * LSTR + kk + quad*8];
      #pragma unroll
      for (int mi = 0; mi < 2; mi++)
        #pragma unroll
        for (int ni = 0; ni < 4; ni++)
          acc[mi][ni] = __builtin_amdgcn_mfma_f32_16x16x32_bf16(
              af[mi], bfr[ni], acc[mi][ni], 0, 0, 0);
    }
  }

  #pragma unroll
  for (int mi = 0; mi < 2; mi++){
    int rbase = row0 + wm + mi * 16 + quad * 4;
    #pragma unroll
    for (int rr = 0; rr < 4; rr++){
      int m = rbase + rr;
      if (m >= M) continue;
      float* op = out + (size_t)m * D_OUT + lm;
      #pragma unroll
      for (int ni = 0; ni < 4; ni++)
        op[ni * 16] = acc[mi][ni][rr];
    }
  }
}

static inline size_t alup(size_t x){ return (x + 255) & ~(size_t)255; }

extern "C" void kernel_launch(void* const* d_in, const int* in_sizes, int n_in,
                              void* d_out, int out_size, void* d_ws, size_t ws_size,
                              hipStream_t stream)
{
  const int*   ei = (const int*)d_in[0];
  const float* xs = (const float*)d_in[1];
  const float* xt = (const float*)d_in[2];
  const float* W0 = (const float*)d_in[3];
  const float* W1 = (const float*)d_in[4];
  const int E   = in_sizes[0] / 2;
  const int n_s = in_sizes[1] / D_IN;
  const int n_t = in_sizes[2] / D_IN;
  const int M   = n_s + n_t;
  const int* src = ei;       // edge_index row 0
  const int* dst = ei + E;   // edge_index row 1 (0-based target index)
  const int nb_t = (n_t + 255) / 256;

  // workspace layout (~29 MB)
  char* p = (char*)d_ws;
  int*   deg    = (int*)p;    p += alup((size_t)n_t * 4);
  int*   off    = (int*)p;    p += alup((size_t)n_t * 4);
  int*   cursor = (int*)p;    p += alup((size_t)n_t * 4);
  float* dinv   = (float*)p;  p += alup((size_t)n_t * 4);
  int*   bsum   = (int*)p;    p += alup((size_t)nb_t * 4);
  int*   csr    = (int*)p;    p += alup((size_t)E * 4);
  u16*   W0t    = (u16*)p;    p += alup((size_t)D_H * D_IN * 2);
  u16*   W1t    = (u16*)p;    p += alup((size_t)D_OUT * D_H * 2);
  u16*   h1     = (u16*)p;    p += alup((size_t)M * D_H * 2);

  const int wprep_n = 128*256 + 64*128 + n_t;
  k_wprep <<<(wprep_n + 255) / 256, 256, 0, stream>>>(W0, W1, W0t, W1t, deg, n_t);
  k_deg   <<<(E + 255) / 256, 256, 0, stream>>>(dst, E, deg);
  k_bsum  <<<nb_t, 256, 0, stream>>>(deg, n_t, bsum);
  k_bscan <<<1, 256, 0, stream>>>(bsum, nb_t);
  k_off   <<<nb_t, 256, 0, stream>>>(deg, n_t, bsum, off, cursor, dinv);
  k_fill  <<<(E + 255) / 256, 256, 0, stream>>>(src, dst, E, cursor, csr);

  // layer 1: h1 = X @ W0 (raw, all rows, bf16)
  k_gemm1<<<(M + 127) / 128, 256, 0, stream>>>(xs, xt, W0t, M, n_s, h1);
  // fused agg: h1 target rows <- u_t (single gather pass for both layers)
  k_aggf <<<(n_t + 3) / 4, 256, 0, stream>>>(off, deg, csr, dinv, h1, n_s, n_t);
  // layer 2: d_out = [relu(h1_s); u_t] @ W1  (final output, no post-pass)
  k_gemm2<<<(M + 127) / 128, 256, 0, stream>>>(h1, W1t, M, n_s, (float*)d_out);
}